// Round 9
// baseline (244.399 us; speedup 1.0000x reference)
//
#include <hip/hip_runtime.h>

// 21-qubit statevector policy net — SINGLE persistent kernel.
// psi accessed with sc0 sc1 (XCD-L2 bypass, Infinity-Cache coherent) => no fences needed
// at grid barriers; barrier = 64 spread counters + block0 wave-poll + flag.
// R9: fix inline-asm operands (ext_vector_type, not HIP float4 struct).
// ws: psi (2^21 float2, 16MB) | partials (552*22 f32, zeroed) @16MB | cnt @+48K | flag @+56K
#define NQ 21
#define DIM (1 << NQ)
#define NL 4
#define ADIM 18
#define GB 512   // blocks; co-residency: 2/CU (8 waves*2<=32, 33KB LDS*2<=160K, VGPR<=128)
#define NT 512

typedef float vf4 __attribute__((ext_vector_type(4)));   // native vector: legal "v" asm operand

__device__ __forceinline__ float2 cfma2(float2 u0, float2 a, float2 u1, float2 b) {
    return make_float2(u0.x * a.x - u0.y * a.y + u1.x * b.x - u1.y * b.y,
                       u0.x * a.y + u0.y * a.x + u1.x * b.y + u1.y * b.x);
}

struct GateU { float2 u00, u01, u10, u11; };

__device__ __forceinline__ void bfly(float2& a, float2& b, const GateU& U) {
    float2 na = cfma2(U.u00, a, U.u01, b);
    float2 nb = cfma2(U.u10, a, U.u11, b);
    a = na; b = nb;
}

// LDS bank swizzle (verified R6/R7)
__device__ __forceinline__ int sw(int j) { return j ^ (((j >> 4) & 7) << 1); }

// ---- LLC-coherent access helpers (sc0 sc1 = what agent-scope atomics emit on gfx950) ----
__device__ __forceinline__ void load4x16_sc(const float* p0, const float* p1,
                                            const float* p2, const float* p3,
                                            vf4& w0, vf4& w1, vf4& w2, vf4& w3) {
    asm volatile(
        "global_load_dwordx4 %0, %4, off sc0 sc1\n\t"
        "global_load_dwordx4 %1, %5, off sc0 sc1\n\t"
        "global_load_dwordx4 %2, %6, off sc0 sc1\n\t"
        "global_load_dwordx4 %3, %7, off sc0 sc1\n\t"
        "s_waitcnt vmcnt(0)"
        : "=&v"(w0), "=&v"(w1), "=&v"(w2), "=&v"(w3)
        : "v"(p0), "v"(p1), "v"(p2), "v"(p3)
        : "memory");
}
__device__ __forceinline__ void store16_sc(float* p, vf4 v) {
    asm volatile("global_store_dwordx4 %0, %1, off sc0 sc1" :: "v"(p), "v"(v) : "memory");
}
__device__ __forceinline__ void store4_sc(float* p, float v) {
    asm volatile("global_store_dword %0, %1, off sc0 sc1" :: "v"(p), "v"(v) : "memory");
}
__device__ __forceinline__ void store4i_sc(int* p, int v) {
    asm volatile("global_store_dword %0, %1, off sc0 sc1" :: "v"(p), "v"(v) : "memory");
}
__device__ __forceinline__ int load_sc_i(const int* p) {
    int r;
    asm volatile("global_load_dword %0, %1, off sc0 sc1\n\ts_waitcnt vmcnt(0)"
                 : "=v"(r) : "v"(p) : "memory");
    return r;
}
__device__ __forceinline__ void load4x4_sc(const float* p0, const float* p1,
                                           const float* p2, const float* p3,
                                           float& a, float& b, float& c, float& d) {
    asm volatile(
        "global_load_dword %0, %4, off sc0 sc1\n\t"
        "global_load_dword %1, %5, off sc0 sc1\n\t"
        "global_load_dword %2, %6, off sc0 sc1\n\t"
        "global_load_dword %3, %7, off sc0 sc1\n\t"
        "s_waitcnt vmcnt(0)"
        : "=&v"(a), "=&v"(b), "=&v"(c), "=&v"(d)
        : "v"(p0), "v"(p1), "v"(p2), "v"(p3)
        : "memory");
}
__device__ __forceinline__ void drain_vmem() {
    asm volatile("s_waitcnt vmcnt(0)" ::: "memory");
}

// grid barrier: no fences (psi is sc-coherent already). 64 counter lines (128B apart),
// block0 wave-polls the 64 counters, publishes monotone flag; others poll flag.
__device__ __forceinline__ void gbar(int* cnt, int* flag, int phase, int tid, int blk) {
    drain_vmem();                        // my sc stores are at LLC once vmcnt retires
    __syncthreads();
    if (tid == 0) atomicAdd(&cnt[(blk & 63) << 5], 1);
    if (blk == 0) {
        if (tid < 64) {
            const int target = (phase + 1) * GB;
            while (true) {
                int vv = load_sc_i(&cnt[tid << 5]);
                for (int o = 32; o; o >>= 1) vv += __shfl_down(vv, o, 64);
                vv = __shfl(vv, 0, 64);
                if (vv >= target) break;
                __builtin_amdgcn_s_sleep(8);
            }
            if (tid == 0) store4i_sc(flag, phase + 1);
        }
        __syncthreads();
    } else {
        if (tid == 0) {
            const int target = phase + 1;
            while (load_sc_i(flag) < target) __builtin_amdgcn_s_sleep(8);
        }
        __syncthreads();
    }
}

// threads 0..20: fused U = RZ*RY*RX for this layer (hidden under in-flight loads)
__device__ __forceinline__ void make_mats(GateU* mats, const float* __restrict__ cp, int layer, int tid) {
    if (tid < NQ) {
        const float* ang = cp + (layer * NQ + tid) * 3;
        float a = ang[0], b = ang[1], c = ang[2];
        float ca = cosf(0.5f * a), sa = sinf(0.5f * a);
        float cb = cosf(0.5f * b), sb = sinf(0.5f * b);
        float cc = cosf(0.5f * c), sc = sinf(0.5f * c);
        float2 m00 = make_float2(cb * ca,  sb * sa);
        float2 m01 = make_float2(-sb * ca, -cb * sa);
        float2 m10 = make_float2(sb * ca,  -cb * sa);
        float2 m11 = make_float2(cb * ca,  -sb * sa);
        GateU U;
        U.u00 = make_float2(cc * m00.x + sc * m00.y, cc * m00.y - sc * m00.x);
        U.u01 = make_float2(cc * m01.x + sc * m01.y, cc * m01.y - sc * m01.x);
        U.u10 = make_float2(cc * m10.x - sc * m10.y, cc * m10.y + sc * m10.x);
        U.u11 = make_float2(cc * m11.x - sc * m11.y, cc * m11.y + sc * m11.x);
        mats[tid] = U;
    }
}

// radix-8 round: 3 gates per LDS round-trip (verified R7)
__device__ __forceinline__ void round3(float2* tile, int tid, int g,
                                       GateU Ua, GateU Ub, GateU Uc) {
    int bl = (1 << g) - 1;
    int base = (tid & bl) | ((tid >> g) << (g + 3));
    float2 v[8];
#pragma unroll
    for (int j = 0; j < 8; ++j) v[j] = tile[sw(base + (j << g))];
#pragma unroll
    for (int s = 0; s < 8; s += 2) bfly(v[s], v[s + 1], Ua);
#pragma unroll
    for (int s = 0; s < 8; ++s) if (!(s & 2)) bfly(v[s], v[s | 2], Ub);
#pragma unroll
    for (int s = 0; s < 8; ++s) if (!(s & 4)) bfly(v[s], v[s | 4], Uc);
#pragma unroll
    for (int j = 0; j < 8; ++j) tile[sw(base + (j << g))] = v[j];
    __syncthreads();
}

__global__ __launch_bounds__(NT, 4) void qpn_kernel(
    const float* __restrict__ state, const float* __restrict__ cp,
    const float* __restrict__ head_w, const float* __restrict__ head_b,
    float* __restrict__ out, float2* __restrict__ psi,
    float* __restrict__ partials, int* __restrict__ cnt, int* __restrict__ flag)
{
    __shared__ float2 tile[4096];
    __shared__ GateU mats[NQ];
    __shared__ float meas[NQ];
    __shared__ float lg[ADIM];
    const int tid = threadIdx.x, blk = blockIdx.x;
    float* psif = (float*)psi;            // float index = float4 index * 4
    float4* t4 = (float4*)tile;

    for (int layer = 0; layer < NL; ++layer) {
        // ======== B phase: h = bits 12..20 (qubits 0..8), l = bits 0..2; block = bits 3..11
        if (layer == 0) {
            const float4* s4 = (const float4*)state;   // input, read-only: normal loads fine
            for (int it = 0; it < 2; ++it) {
                int f2 = it * NT + tid;
                int h = f2 >> 1, c2 = f2 & 1;
                float4 w = s4[(h << 10) | (blk << 1) | c2];
                int j = 8 * h + 4 * c2;
                t4[sw(j) >> 1]     = make_float4(w.x, 0.f, w.y, 0.f);
                t4[sw(j + 2) >> 1] = make_float4(w.z, 0.f, w.w, 0.f);
            }
            make_mats(mats, cp, layer, tid);
            __syncthreads();
            round3(tile, tid, 3, mats[8], mats[7], mats[6]);   // q8,q7,q6
            round3(tile, tid, 6, mats[5], mats[4], mats[3]);   // q5,q4,q3
            round3(tile, tid, 9, mats[2], mats[1], mats[0]);   // q2,q1,q0
        } else {
            float2 v[8];
            vf4 w[4];
            {
                int f0 = tid,          h0 = f0 >> 2, c0 = f0 & 3;
                int f1 = NT + tid,     h1 = f1 >> 2, c1 = f1 & 3;
                int f2 = 2 * NT + tid, h2 = f2 >> 2, c2 = f2 & 3;
                int f3 = 3 * NT + tid, h3 = f3 >> 2, c3 = f3 & 3;
                load4x16_sc(psif + 4 * (size_t)((h0 << 11) | (blk << 2) | c0),
                            psif + 4 * (size_t)((h1 << 11) | (blk << 2) | c1),
                            psif + 4 * (size_t)((h2 << 11) | (blk << 2) | c2),
                            psif + 4 * (size_t)((h3 << 11) | (blk << 2) | c3),
                            w[0], w[1], w[2], w[3]);
            }
            make_mats(mats, cp, layer, tid);
            __syncthreads();
            // c4 (prev layer's wrap CNOT(0->q20)): odd slot => slot bit11 flip = w[i^2]
#pragma unroll
            for (int i = 0; i < 4; ++i) {
                v[2 * i]     = make_float2(w[i].x, w[i].y);
                v[2 * i + 1] = make_float2(w[i ^ 2].z, w[i ^ 2].w);
            }
            // register gates: q0 (slot bit11 = v bit2), q1 (slot bit10 = v bit1)
            GateU U0 = mats[0];
#pragma unroll
            for (int s = 0; s < 8; ++s) if (!(s & 4)) bfly(v[s], v[s | 4], U0);
            GateU U1 = mats[1];
#pragma unroll
            for (int s = 0; s < 8; ++s) if (!(s & 2)) bfly(v[s], v[s | 2], U1);
            for (int i = 0; i < 4; ++i)
                t4[sw(2 * (i * NT + tid)) >> 1] =
                    make_float4(v[2 * i].x, v[2 * i].y, v[2 * i + 1].x, v[2 * i + 1].y);
            __syncthreads();
            round3(tile, tid, 3, mats[8], mats[7], mats[6]);   // q8,q7,q6
            round3(tile, tid, 6, mats[5], mats[4], mats[3]);   // q5,q4,q3
            {   // lone sweep: q2 (slot bit9)
                GateU U = mats[2];
                for (int it = 0; it < 4; ++it) {
                    int p = it * NT + tid;
                    int i0 = ((p >> 9) << 10) | (p & 511);
                    bfly(tile[sw(i0)], tile[sw(i0 | 512)], U);
                }
                __syncthreads();
            }
        }
        // store: src h = h ^ ((h>>1)&0xFF) for layers 0..2 (B-local CNOT chain), identity layer 3
        {
            int srcmask = (layer < 3) ? 0xFF : 0;
            for (int i = 0; i < 4; ++i) {
                int f = i * NT + tid;
                int h = f >> 2, c = f & 3;
                int hs = h ^ ((h >> 1) & srcmask);
                int j = sw(hs * 8 + 2 * c);
                float2 e0 = tile[j], e1 = tile[j + 1];
                vf4 val = {e0.x, e0.y, e1.x, e1.y};
                store16_sc(psif + 4 * (size_t)((h << 11) | (blk << 2) | c), val);
            }
        }
        gbar(cnt, flag, 2 * layer, tid, blk);

        // ======== A phase: bits 0..11 local (qubits 9..20); block = bits 12..20
        {
            float* ga = psif + (size_t)blk * 8192;   // 2048 float4 = 8192 floats
            float2 v[8];
            vf4 w[4];
            load4x16_sc(ga + 4 * (size_t)tid, ga + 4 * (size_t)(NT + tid),
                        ga + 4 * (size_t)(2 * NT + tid), ga + 4 * (size_t)(3 * NT + tid),
                        w[0], w[1], w[2], w[3]);
            // mats for this layer already in LDS from B phase
#pragma unroll
            for (int i = 0; i < 4; ++i) {
                v[2 * i]     = make_float2(w[i].x, w[i].y);
                v[2 * i + 1] = make_float2(w[i].z, w[i].w);
            }
            // register gates: q20 (slot bit0), q10 (slot bit10 = v bit1), q9 (slot bit11 = v bit2)
            GateU U20 = mats[20];
#pragma unroll
            for (int s = 0; s < 8; s += 2) bfly(v[s], v[s + 1], U20);
            GateU U10 = mats[10];
#pragma unroll
            for (int s = 0; s < 8; ++s) if (!(s & 2)) bfly(v[s], v[s | 2], U10);
            GateU U9 = mats[9];
#pragma unroll
            for (int s = 0; s < 8; ++s) if (!(s & 4)) bfly(v[s], v[s | 4], U9);
            for (int i = 0; i < 4; ++i)
                t4[sw(2 * (i * NT + tid)) >> 1] =
                    make_float4(v[2 * i].x, v[2 * i].y, v[2 * i + 1].x, v[2 * i + 1].y);
        }
        __syncthreads();
        round3(tile, tid, 1, mats[19], mats[18], mats[17]);    // q19,q18,q17
        round3(tile, tid, 4, mats[16], mats[15], mats[14]);    // q16,q15,q14
        round3(tile, tid, 7, mats[13], mats[12], mats[11]);    // q13,q12,q11

        if (layer < 3) {
            // boundary CNOT (ctrl = stored bit12 = blk&1, tgt bit11) + A-local chain, as gather
            float* oa = psif + (size_t)blk * 8192;
            int cb = (blk & 1) << 11;
            for (int i = 0; i < 4; ++i) {
                int f = i * NT + tid;
                int s0 = ((2 * f) ^ (f & 0x7FF)) ^ cb;
                float2 e0 = tile[sw(s0)], e1 = tile[sw(s0 ^ 1)];
                vf4 val = {e0.x, e0.y, e1.x, e1.y};
                store16_sc(oa + 4 * (size_t)f, val);
            }
            gbar(cnt, flag, 2 * layer + 1, tid, blk);
        } else {
            // measurement: total + per-qubit ones sums
            float tot = 0.f, ones[NQ];
#pragma unroll
            for (int q = 0; q < NQ; ++q) ones[q] = 0.f;
            for (int it = 0; it < 8; ++it) {
                int j = it * NT + tid;
                float2 a2 = tile[sw(j)];
                float pr = a2.x * a2.x + a2.y * a2.y;
                int gidx = (blk << 12) | j;
                tot += pr;
#pragma unroll
                for (int q = 0; q < NQ; ++q)
                    ones[q] += pr * (float)((gidx >> (20 - q)) & 1);
            }
            for (int off = 32; off; off >>= 1) {
                tot += __shfl_down(tot, off, 64);
#pragma unroll
                for (int q = 0; q < NQ; ++q) ones[q] += __shfl_down(ones[q], off, 64);
            }
            __syncthreads();
            float* red = (float*)tile;
            int wv = tid >> 6, ln = tid & 63;
            if (ln == 0) {
                red[wv * 22 + 21] = tot;
#pragma unroll
                for (int q = 0; q < NQ; ++q) red[wv * 22 + q] = ones[q];
            }
            __syncthreads();
            if (tid < 22) {
                float s = 0.f;
                for (int wvi = 0; wvi < 8; ++wvi) s += red[wvi * 22 + tid];
                store4_sc(&partials[blk * 22 + tid], s);
            }
            // final arrival; non-zero blocks exit
            drain_vmem();
            __syncthreads();
            if (tid == 0) atomicAdd(&cnt[(blk & 63) << 5], 1);
            if (blk != 0) return;
            if (tid < 64) {
                while (true) {
                    int vv = load_sc_i(&cnt[tid << 5]);
                    for (int o = 32; o; o >>= 1) vv += __shfl_down(vv, o, 64);
                    vv = __shfl(vv, 0, 64);
                    if (vv >= 8 * GB) break;
                    __builtin_amdgcn_s_sleep(8);
                }
            }
            __syncthreads();
        }
    }

    // ======== block 0: reduce partials (sc, batched) -> meas -> head -> softmax
    {
        float* red = (float*)tile;
        int col = tid % 22, grp = tid / 22;
        if (tid < 506) {
            float s = 0.f;
            const float* base = partials + col;
#pragma unroll
            for (int kk = 0; kk < 6; ++kk) {    // r = grp + 23k, k=0..23 (padded region zeroed)
                int r0 = grp + 92 * kk;
                float a, b, c, d;
                load4x4_sc(base + (size_t)r0 * 22, base + (size_t)(r0 + 23) * 22,
                           base + (size_t)(r0 + 46) * 22, base + (size_t)(r0 + 69) * 22,
                           a, b, c, d);
                s += a + b + c + d;
            }
            red[grp * 22 + col] = s;
        }
        __syncthreads();
        if (tid < 22) {
            float t2 = 0.f;
            for (int g = 0; g < 23; ++g) t2 += red[g * 22 + tid];
            red[600 + tid] = t2;
        }
        __syncthreads();
        if (tid < NQ) {
            float tot = red[600 + 21];
            meas[tid] = (tot > 0.f) ? (1.f - 2.f * red[600 + tid] / tot) : 1.f;
        }
        __syncthreads();
        if (tid < ADIM) {
            float s2 = head_b[tid];
            for (int q = 0; q < NQ; ++q) s2 += head_w[tid * NQ + q] * meas[q];
            lg[tid] = s2;
        }
        __syncthreads();
        if (tid == 0) {
            float m = lg[0];
            for (int a = 1; a < ADIM; ++a) m = fmaxf(m, lg[a]);
            float ssum = 0.f;
            for (int a = 0; a < ADIM; ++a) ssum += expf(lg[a] - m);
            float inv = 1.f / ssum;
            for (int a = 0; a < ADIM; ++a) out[a] = expf(lg[a] - m) * inv;
        }
    }
}

extern "C" void kernel_launch(void* const* d_in, const int* in_sizes, int n_in,
                              void* d_out, int out_size, void* d_ws, size_t ws_size,
                              hipStream_t stream) {
    const float* state   = (const float*)d_in[0];
    const float* cparams = (const float*)d_in[1];
    const float* head_w  = (const float*)d_in[2];
    const float* head_b  = (const float*)d_in[3];
    float* out = (float*)d_out;

    char* ws = (char*)d_ws;
    float2* psi      = (float2*)ws;
    float*  partials = (float*)(ws + (size_t)DIM * 8);             // 552*22 floats (padded, zeroed)
    int*    cnt      = (int*)  (ws + (size_t)DIM * 8 + 49152);     // 64 lines * 128B
    int*    flag     = (int*)  (ws + (size_t)DIM * 8 + 49152 + 8192);

    hipMemsetAsync(ws + (size_t)DIM * 8, 0, 49152 + 8192 + 128, stream);
    qpn_kernel<<<GB, NT, 0, stream>>>(state, cparams, head_w, head_b, out,
                                      psi, partials, cnt, flag);
}

// Round 10
// 214.897 us; speedup vs baseline: 1.1373x; 1.1373x over previous
//
#include <hip/hip_runtime.h>

// 21-qubit statevector policy net — per-phase kernels (R7 structure).
// R10: B pass re-tiled to 8192-complex blocks (l = 4 low bits => 128B-aligned
// full-line chunks, single-owner). 2 x 32KB LDS halves; all 9 B gates via the
// verified round3(g=3,6,9); c4 folded into LDS scatter at load.
// ws: psi (2^21 float2, 16MB) | partials (512*22 f32) @16MB
#define NQ 21
#define DIM (1 << NQ)
#define NL 4
#define ADIM 18
#define GBA 512  // A-pass blocks
#define GBB 256  // B-pass blocks (8192-complex tiles)
#define NT 512

__device__ __forceinline__ float2 cfma2(float2 u0, float2 a, float2 u1, float2 b) {
    return make_float2(u0.x * a.x - u0.y * a.y + u1.x * b.x - u1.y * b.y,
                       u0.x * a.y + u0.y * a.x + u1.x * b.y + u1.y * b.x);
}

struct GateU { float2 u00, u01, u10, u11; };

__device__ __forceinline__ void bfly(float2& a, float2& b, const GateU& U) {
    float2 na = cfma2(U.u00, a, U.u01, b);
    float2 nb = cfma2(U.u10, a, U.u11, b);
    a = na; b = nb;
}

// LDS bank swizzle (verified R6/R7)
__device__ __forceinline__ int sw(int j) { return j ^ (((j >> 4) & 7) << 1); }

// threads 0..20: fused U = RZ*RY*RX for this layer (hidden under global loads)
__device__ __forceinline__ void make_mats(GateU* mats, const float* __restrict__ cp, int layer, int tid) {
    if (tid < NQ) {
        const float* ang = cp + (layer * NQ + tid) * 3;
        float a = ang[0], b = ang[1], c = ang[2];
        float ca = cosf(0.5f * a), sa = sinf(0.5f * a);
        float cb = cosf(0.5f * b), sb = sinf(0.5f * b);
        float cc = cosf(0.5f * c), sc = sinf(0.5f * c);
        float2 m00 = make_float2(cb * ca,  sb * sa);
        float2 m01 = make_float2(-sb * ca, -cb * sa);
        float2 m10 = make_float2(sb * ca,  -cb * sa);
        float2 m11 = make_float2(cb * ca,  -sb * sa);
        GateU U;
        U.u00 = make_float2(cc * m00.x + sc * m00.y, cc * m00.y - sc * m00.x);
        U.u01 = make_float2(cc * m01.x + sc * m01.y, cc * m01.y - sc * m01.x);
        U.u10 = make_float2(cc * m10.x - sc * m10.y, cc * m10.y + sc * m10.x);
        U.u11 = make_float2(cc * m11.x - sc * m11.y, cc * m11.y + sc * m11.x);
        mats[tid] = U;
    }
}

// radix-8 round: 3 gates per LDS round-trip (verified R7)
__device__ __forceinline__ void round3(float2* tile, int tid, int g,
                                       GateU Ua, GateU Ub, GateU Uc) {
    int bl = (1 << g) - 1;
    int base = (tid & bl) | ((tid >> g) << (g + 3));
    float2 v[8];
#pragma unroll
    for (int j = 0; j < 8; ++j) v[j] = tile[sw(base + (j << g))];
#pragma unroll
    for (int s = 0; s < 8; s += 2) bfly(v[s], v[s + 1], Ua);
#pragma unroll
    for (int s = 0; s < 8; ++s) if (!(s & 2)) bfly(v[s], v[s | 2], Ub);
#pragma unroll
    for (int s = 0; s < 8; ++s) if (!(s & 4)) bfly(v[s], v[s | 4], Uc);
#pragma unroll
    for (int j = 0; j < 8; ++j) tile[sw(base + (j << g))] = v[j];
    __syncthreads();
}

// B pass: complex idx = (h<<12)|(blk<<4)|l; h = bits 12..20 (qubits 0..8, h bit j = qubit 8-j),
// blk = bits 4..11 (256 blocks), l = bits 0..3. Per (h,blk): 16 complex = 128B full line.
// Two LDS halves by l: half H covers l in [8H, 8H+8); slot = (h<<3)|(l&7) (gates only touch h).
__global__ __launch_bounds__(NT, 4) void k_passB(const float* __restrict__ state,
                                                 float2* __restrict__ psi,
                                                 const float* __restrict__ cp, int layer) {
    __shared__ float2 tile[4096];
    __shared__ GateU mats[NQ];
    const int tid = threadIdx.x, blk = blockIdx.x;
    float4* psi4 = (float4*)psi;

    make_mats(mats, cp, layer, tid);
    const int srcmask = (layer < 3) ? 0xFF : 0;

    for (int H = 0; H < 2; ++H) {
        if (H) __syncthreads();                 // LDS reuse vs prior half's store-gather
        if (layer == 0) {
            const float4* s4 = (const float4*)state;   // float idx == complex idx
            for (int i = 0; i < 2; ++i) {
                int f = i * NT + tid;                  // 1024 state-float4 per half
                int d = f & 1, h = f >> 1;
                float4 w = s4[(h << 10) | (blk << 2) | (2 * H + d)];
                int s = (h << 3) | (4 * d);
                tile[sw(s)]     = make_float2(w.x, 0.f);
                tile[sw(s + 1)] = make_float2(w.y, 0.f);
                tile[sw(s + 2)] = make_float2(w.z, 0.f);
                tile[sw(s + 3)] = make_float2(w.w, 0.f);
            }
        } else {
            for (int i = 0; i < 4; ++i) {
                int f = i * NT + tid;                  // 2048 psi-float4 per half
                int c = f & 3, h = f >> 2;
                float4 w = psi4[(h << 11) | (blk << 3) | (4 * H + c)];
                int se = (h << 3) | (2 * c);
                // c4 (prev layer's CNOT q20->q0): l odd => flip bit 20 = h bit 8 = slot bit 11
                tile[sw(se)]            = make_float2(w.x, w.y);
                tile[sw((se + 1) ^ 2048)] = make_float2(w.z, w.w);
            }
        }
        __syncthreads();
        round3(tile, tid, 3, mats[8], mats[7], mats[6]);   // q8,q7,q6  (h bits 0..2)
        round3(tile, tid, 6, mats[5], mats[4], mats[3]);   // q5,q4,q3  (h bits 3..5)
        round3(tile, tid, 9, mats[2], mats[1], mats[0]);   // q2,q1,q0  (h bits 6..8)
        // store: B-local CNOT chain (q0->q1 ... q7->q8) as gather: src h = h ^ ((h>>1)&0xFF)
        for (int i = 0; i < 4; ++i) {
            int f = i * NT + tid;
            int c = f & 3, h = f >> 2;
            int hs = h ^ ((h >> 1) & srcmask);
            int s = (hs << 3) | (2 * c);
            float2 e0 = tile[sw(s)], e1 = tile[sw(s + 1)];
            psi4[(h << 11) | (blk << 3) | (4 * H + c)] = make_float4(e0.x, e0.y, e1.x, e1.y);
        }
    }
}

// A pass: bits 0..11 local (qubits 9..20, slot bit k <-> qubit 20-k); block = bits 12..20.
// Verbatim R7 (verified).
__global__ __launch_bounds__(NT, 4) void k_passA(float2* __restrict__ psi,
                                                 const float* __restrict__ cp, int layer,
                                                 float* __restrict__ partials) {
    __shared__ float2 tile[4096];
    __shared__ GateU mats[NQ];
    const int tid = threadIdx.x, blk = blockIdx.x;
    float4* psi4 = (float4*)psi;
    float4* t4 = (float4*)tile;

    {
        const float4* ga = psi4 + (size_t)blk * 2048;
        float2 v[8];
        float4 w[4];
        for (int i = 0; i < 4; ++i) w[i] = ga[i * NT + tid];
        make_mats(mats, cp, layer, tid);
        __syncthreads();
#pragma unroll
        for (int i = 0; i < 4; ++i) {
            v[2 * i]     = make_float2(w[i].x, w[i].y);
            v[2 * i + 1] = make_float2(w[i].z, w[i].w);
        }
        // register gates: q20 (slot bit0), q10 (slot bit10 = v bit1), q9 (slot bit11 = v bit2)
        GateU U20 = mats[20];
#pragma unroll
        for (int s = 0; s < 8; s += 2) bfly(v[s], v[s + 1], U20);
        GateU U10 = mats[10];
#pragma unroll
        for (int s = 0; s < 8; ++s) if (!(s & 2)) bfly(v[s], v[s | 2], U10);
        GateU U9 = mats[9];
#pragma unroll
        for (int s = 0; s < 8; ++s) if (!(s & 4)) bfly(v[s], v[s | 4], U9);
        for (int i = 0; i < 4; ++i)
            t4[sw(2 * (i * NT + tid)) >> 1] =
                make_float4(v[2 * i].x, v[2 * i].y, v[2 * i + 1].x, v[2 * i + 1].y);
    }
    __syncthreads();
    round3(tile, tid, 1, mats[19], mats[18], mats[17]);    // q19,q18,q17
    round3(tile, tid, 4, mats[16], mats[15], mats[14]);    // q16,q15,q14
    round3(tile, tid, 7, mats[13], mats[12], mats[11]);    // q13,q12,q11

    if (layer < 3) {
        // boundary CNOT (ctrl = stored bit12 = blk&1, tgt bit11) + A-local chain, as gather
        float4* oa = psi4 + (size_t)blk * 2048;
        int cb = (blk & 1) << 11;
        for (int i = 0; i < 4; ++i) {
            int f = i * NT + tid;
            int s0 = ((2 * f) ^ (f & 0x7FF)) ^ cb;
            float2 e0 = tile[sw(s0)], e1 = tile[sw(s0 ^ 1)];
            oa[f] = make_float4(e0.x, e0.y, e1.x, e1.y);
        }
    } else {
        // measurement: total + per-qubit ones sums (normalization folded in at k_final)
        float tot = 0.f, ones[NQ];
#pragma unroll
        for (int q = 0; q < NQ; ++q) ones[q] = 0.f;
        for (int it = 0; it < 8; ++it) {
            int j = it * NT + tid;
            float2 a2 = tile[sw(j)];
            float pr = a2.x * a2.x + a2.y * a2.y;
            int gidx = (blk << 12) | j;
            tot += pr;
#pragma unroll
            for (int q = 0; q < NQ; ++q)
                ones[q] += pr * (float)((gidx >> (20 - q)) & 1);
        }
        for (int off = 32; off; off >>= 1) {
            tot += __shfl_down(tot, off, 64);
#pragma unroll
            for (int q = 0; q < NQ; ++q) ones[q] += __shfl_down(ones[q], off, 64);
        }
        __syncthreads();
        float* red = (float*)tile;
        int wv = tid >> 6, ln = tid & 63;
        if (ln == 0) {
            red[wv * 22 + 21] = tot;
#pragma unroll
            for (int q = 0; q < NQ; ++q) red[wv * 22 + q] = ones[q];
        }
        __syncthreads();
        if (tid < 22) {
            float s = 0.f;
            for (int wvi = 0; wvi < 8; ++wvi) s += red[wvi * 22 + tid];
            partials[blk * 22 + tid] = s;
        }
    }
}

// Reduce 512 partial rows -> meas -> head -> softmax (verbatim R7)
__global__ __launch_bounds__(NT) void k_final(const float* __restrict__ partials,
                                              const float* __restrict__ head_w,
                                              const float* __restrict__ head_b,
                                              float* __restrict__ out) {
    __shared__ float red[640];
    __shared__ float meas[NQ];
    __shared__ float lg[ADIM];
    int tid = threadIdx.x;
    int col = tid % 22, grp = tid / 22;
    if (tid < 506) {
        float s = 0.f;
        for (int r = grp; r < GBA; r += 23) s += partials[r * 22 + col];
        red[grp * 22 + col] = s;
    }
    __syncthreads();
    if (tid < 22) {
        float t2 = 0.f;
        for (int g = 0; g < 23; ++g) t2 += red[g * 22 + tid];
        red[600 + tid] = t2;
    }
    __syncthreads();
    if (tid < NQ) {
        float tot = red[600 + 21];
        meas[tid] = (tot > 0.f) ? (1.f - 2.f * red[600 + tid] / tot) : 1.f;
    }
    __syncthreads();
    if (tid < ADIM) {
        float s2 = head_b[tid];
        for (int q = 0; q < NQ; ++q) s2 += head_w[tid * NQ + q] * meas[q];
        lg[tid] = s2;
    }
    __syncthreads();
    if (tid == 0) {
        float m = lg[0];
        for (int a = 1; a < ADIM; ++a) m = fmaxf(m, lg[a]);
        float ssum = 0.f;
        for (int a = 0; a < ADIM; ++a) ssum += expf(lg[a] - m);
        float inv = 1.f / ssum;
        for (int a = 0; a < ADIM; ++a) out[a] = expf(lg[a] - m) * inv;
    }
}

extern "C" void kernel_launch(void* const* d_in, const int* in_sizes, int n_in,
                              void* d_out, int out_size, void* d_ws, size_t ws_size,
                              hipStream_t stream) {
    const float* state   = (const float*)d_in[0];
    const float* cparams = (const float*)d_in[1];
    const float* head_w  = (const float*)d_in[2];
    const float* head_b  = (const float*)d_in[3];
    float* out = (float*)d_out;

    float2* psi      = (float2*)d_ws;
    float*  partials = (float*)((char*)d_ws + (size_t)DIM * 8);

    for (int layer = 0; layer < NL; ++layer) {
        k_passB<<<GBB, NT, 0, stream>>>(state, psi, cparams, layer);
        k_passA<<<GBA, NT, 0, stream>>>(psi, cparams, layer, partials);
    }
    k_final<<<1, NT, 0, stream>>>(partials, head_w, head_b, out);
}

// Round 11
// 197.563 us; speedup vs baseline: 1.2371x; 1.0877x over previous
//
#include <hip/hip_runtime.h>

// 21-qubit statevector policy net — per-phase kernels, software-pipelined.
// R11: A pass = 2 tiles/block (grid 256, dual 32KB LDS buffers, loads hoisted);
//      B pass = dual-buffer halves (loads hoisted); k_final folded into A3
//      (last-block-done + sc partials). All index algebra verbatim R7/R10 (verified).
// ws: psi (2^21 float2, 16MB) | partials (256*22 f32) @16MB | done @16MB+32K
#define NQ 21
#define DIM (1 << NQ)
#define NL 4
#define ADIM 18
#define GB 256   // blocks per pass
#define NT 512

__device__ __forceinline__ float2 cfma2(float2 u0, float2 a, float2 u1, float2 b) {
    return make_float2(u0.x * a.x - u0.y * a.y + u1.x * b.x - u1.y * b.y,
                       u0.x * a.y + u0.y * a.x + u1.x * b.y + u1.y * b.x);
}

struct GateU { float2 u00, u01, u10, u11; };

__device__ __forceinline__ void bfly(float2& a, float2& b, const GateU& U) {
    float2 na = cfma2(U.u00, a, U.u01, b);
    float2 nb = cfma2(U.u10, a, U.u11, b);
    a = na; b = nb;
}

// LDS bank swizzle (verified R6/R7/R10)
__device__ __forceinline__ int sw(int j) { return j ^ (((j >> 4) & 7) << 1); }

// sc0 sc1 = LLC-coherent, XCD-L2 bypass (verified R9)
__device__ __forceinline__ void store4_sc(float* p, float v) {
    asm volatile("global_store_dword %0, %1, off sc0 sc1" :: "v"(p), "v"(v) : "memory");
}
__device__ __forceinline__ float load_sc_f(const float* p) {
    float r;
    asm volatile("global_load_dword %0, %1, off sc0 sc1\n\ts_waitcnt vmcnt(0)"
                 : "=v"(r) : "v"(p) : "memory");
    return r;
}
__device__ __forceinline__ void drain_vmem() {
    asm volatile("s_waitcnt vmcnt(0)" ::: "memory");
}

// threads 0..20: fused U = RZ*RY*RX for this layer (hidden under global loads)
__device__ __forceinline__ void make_mats(GateU* mats, const float* __restrict__ cp, int layer, int tid) {
    if (tid < NQ) {
        const float* ang = cp + (layer * NQ + tid) * 3;
        float a = ang[0], b = ang[1], c = ang[2];
        float ca = cosf(0.5f * a), sa = sinf(0.5f * a);
        float cb = cosf(0.5f * b), sb = sinf(0.5f * b);
        float cc = cosf(0.5f * c), sc = sinf(0.5f * c);
        float2 m00 = make_float2(cb * ca,  sb * sa);
        float2 m01 = make_float2(-sb * ca, -cb * sa);
        float2 m10 = make_float2(sb * ca,  -cb * sa);
        float2 m11 = make_float2(cb * ca,  -sb * sa);
        GateU U;
        U.u00 = make_float2(cc * m00.x + sc * m00.y, cc * m00.y - sc * m00.x);
        U.u01 = make_float2(cc * m01.x + sc * m01.y, cc * m01.y - sc * m01.x);
        U.u10 = make_float2(cc * m10.x - sc * m10.y, cc * m10.y + sc * m10.x);
        U.u11 = make_float2(cc * m11.x - sc * m11.y, cc * m11.y + sc * m11.x);
        mats[tid] = U;
    }
}

// radix-8 round: 3 gates per LDS round-trip (verified R7)
__device__ __forceinline__ void round3(float2* tile, int tid, int g,
                                       GateU Ua, GateU Ub, GateU Uc) {
    int bl = (1 << g) - 1;
    int base = (tid & bl) | ((tid >> g) << (g + 3));
    float2 v[8];
#pragma unroll
    for (int j = 0; j < 8; ++j) v[j] = tile[sw(base + (j << g))];
#pragma unroll
    for (int s = 0; s < 8; s += 2) bfly(v[s], v[s + 1], Ua);
#pragma unroll
    for (int s = 0; s < 8; ++s) if (!(s & 2)) bfly(v[s], v[s | 2], Ub);
#pragma unroll
    for (int s = 0; s < 8; ++s) if (!(s & 4)) bfly(v[s], v[s | 4], Uc);
#pragma unroll
    for (int j = 0; j < 8; ++j) tile[sw(base + (j << g))] = v[j];
    __syncthreads();
}

// ===== B pass (verified R10 algebra): complex idx = (h<<12)|(blk<<4)|l; h = bits 12..20
// (9 bits, qubits 0..8), blk = bits 4..11, l = bits 0..3 (128B full line per (h,blk)).
// Two l-halves, dual LDS buffers, both halves' loads hoisted.
__global__ __launch_bounds__(NT, 2) void k_passB(const float* __restrict__ state,
                                                 float2* __restrict__ psi,
                                                 const float* __restrict__ cp, int layer) {
    __shared__ float2 tA[4096], tB[4096];
    __shared__ GateU mats[NQ];
    const int tid = threadIdx.x, blk = blockIdx.x;
    float4* psi4 = (float4*)psi;
    const int srcmask = (layer < 3) ? 0xFF : 0;

    float4 wA[4], wB[4];
    if (layer == 0) {
        const float4* s4 = (const float4*)state;
        for (int i = 0; i < 2; ++i) {
            int f = i * NT + tid, d = f & 1, h = f >> 1;
            wA[i] = s4[(h << 10) | (blk << 2) | d];
            wB[i] = s4[(h << 10) | (blk << 2) | (2 + d)];
        }
    } else {
        for (int i = 0; i < 4; ++i) {
            int f = i * NT + tid, c = f & 3, h = f >> 2;
            wA[i] = psi4[(h << 11) | (blk << 3) | c];
            wB[i] = psi4[(h << 11) | (blk << 3) | (4 + c)];
        }
    }
    make_mats(mats, cp, layer, tid);
    __syncthreads();

    // scatter half 0 -> tA (verbatim R10 formulas)
    if (layer == 0) {
        float4* t4 = (float4*)tA;
        for (int i = 0; i < 2; ++i) {
            int f = i * NT + tid, d = f & 1, h = f >> 1;
            int j = (h << 3) | (4 * d);
            float4 w = wA[i];
            t4[sw(j) >> 1]     = make_float4(w.x, 0.f, w.y, 0.f);
            t4[sw(j + 2) >> 1] = make_float4(w.z, 0.f, w.w, 0.f);
        }
    } else {
        for (int i = 0; i < 4; ++i) {
            int f = i * NT + tid, c = f & 3, h = f >> 2;
            int se = (h << 3) | (2 * c);
            float4 w = wA[i];
            // c4 (prev layer's CNOT ctrl q20 -> tgt q0): l odd => flip bit 20 = slot bit 11
            tA[sw(se)]              = make_float2(w.x, w.y);
            tA[sw((se + 1) ^ 2048)] = make_float2(w.z, w.w);
        }
    }
    __syncthreads();
    round3(tA, tid, 3, mats[8], mats[7], mats[6]);
    round3(tA, tid, 6, mats[5], mats[4], mats[3]);
    round3(tA, tid, 9, mats[2], mats[1], mats[0]);

    // store half 0 (chain gather: src h = h ^ ((h>>1)&mask)) + scatter half 1 -> tB
    for (int i = 0; i < 4; ++i) {
        int f = i * NT + tid, c = f & 3, h = f >> 2;
        int hs = h ^ ((h >> 1) & srcmask);
        int s = (hs << 3) | (2 * c);
        float2 e0 = tA[sw(s)], e1 = tA[sw(s + 1)];
        psi4[(h << 11) | (blk << 3) | c] = make_float4(e0.x, e0.y, e1.x, e1.y);
    }
    if (layer == 0) {
        float4* t4 = (float4*)tB;
        for (int i = 0; i < 2; ++i) {
            int f = i * NT + tid, d = f & 1, h = f >> 1;
            int j = (h << 3) | (4 * d);
            float4 w = wB[i];
            t4[sw(j) >> 1]     = make_float4(w.x, 0.f, w.y, 0.f);
            t4[sw(j + 2) >> 1] = make_float4(w.z, 0.f, w.w, 0.f);
        }
    } else {
        for (int i = 0; i < 4; ++i) {
            int f = i * NT + tid, c = f & 3, h = f >> 2;
            int se = (h << 3) | (2 * c);
            float4 w = wB[i];
            tB[sw(se)]              = make_float2(w.x, w.y);
            tB[sw((se + 1) ^ 2048)] = make_float2(w.z, w.w);
        }
    }
    __syncthreads();
    round3(tB, tid, 3, mats[8], mats[7], mats[6]);
    round3(tB, tid, 6, mats[5], mats[4], mats[3]);
    round3(tB, tid, 9, mats[2], mats[1], mats[0]);
    for (int i = 0; i < 4; ++i) {
        int f = i * NT + tid, c = f & 3, h = f >> 2;
        int hs = h ^ ((h >> 1) & srcmask);
        int s = (hs << 3) | (2 * c);
        float2 e0 = tB[sw(s)], e1 = tB[sw(s + 1)];
        psi4[(h << 11) | (blk << 3) | (4 + c)] = make_float4(e0.x, e0.y, e1.x, e1.y);
    }
}

// regscatter for A pass (verbatim R7/R10): reg gates q20,q10,q9 then LDS scatter
__device__ __forceinline__ void a_regscatter(float2* tile, const float4* w,
                                             const GateU* mats, int tid) {
    float2 v[8];
    float4* t4 = (float4*)tile;
#pragma unroll
    for (int i = 0; i < 4; ++i) {
        v[2 * i]     = make_float2(w[i].x, w[i].y);
        v[2 * i + 1] = make_float2(w[i].z, w[i].w);
    }
    GateU U20 = mats[20];
#pragma unroll
    for (int s = 0; s < 8; s += 2) bfly(v[s], v[s + 1], U20);
    GateU U10 = mats[10];
#pragma unroll
    for (int s = 0; s < 8; ++s) if (!(s & 2)) bfly(v[s], v[s | 2], U10);
    GateU U9 = mats[9];
#pragma unroll
    for (int s = 0; s < 8; ++s) if (!(s & 4)) bfly(v[s], v[s | 4], U9);
    for (int i = 0; i < 4; ++i)
        t4[sw(2 * (i * NT + tid)) >> 1] =
            make_float4(v[2 * i].x, v[2 * i].y, v[2 * i + 1].x, v[2 * i + 1].y);
}

__device__ __forceinline__ void a_rounds(float2* tile, const GateU* mats, int tid) {
    round3(tile, tid, 1, mats[19], mats[18], mats[17]);
    round3(tile, tid, 4, mats[16], mats[15], mats[14]);
    round3(tile, tid, 7, mats[13], mats[12], mats[11]);
}

// gather-store with boundary CNOT + A-local chain (verbatim R7)
__device__ __forceinline__ void a_gatherstore(float2* tile, float4* oa, int t, int tid) {
    int cb = (t & 1) << 11;
    for (int i = 0; i < 4; ++i) {
        int f = i * NT + tid;
        int s0 = ((2 * f) ^ (f & 0x7FF)) ^ cb;
        float2 e0 = tile[sw(s0)], e1 = tile[sw(s0 ^ 1)];
        oa[f] = make_float4(e0.x, e0.y, e1.x, e1.y);
    }
}

__device__ __forceinline__ void a_accum(float2* tile, int t, int tid,
                                        float& tot, float* ones) {
    for (int it = 0; it < 8; ++it) {
        int j = it * NT + tid;
        float2 a2 = tile[sw(j)];
        float pr = a2.x * a2.x + a2.y * a2.y;
        int gidx = (t << 12) | j;
        tot += pr;
#pragma unroll
        for (int q = 0; q < NQ; ++q)
            ones[q] += pr * (float)((gidx >> (20 - q)) & 1);
    }
}

// A pass: bits 0..11 local (qubits 9..20); tiles t0=2blk, t1=2blk+1 pipelined.
// Layer 3: measurement + last-block-done final (head+softmax) folded in.
__global__ __launch_bounds__(NT, 2) void k_passA(float2* __restrict__ psi,
                                                 const float* __restrict__ cp, int layer,
                                                 float* __restrict__ partials,
                                                 const float* __restrict__ head_w,
                                                 const float* __restrict__ head_b,
                                                 float* __restrict__ out,
                                                 int* __restrict__ done) {
    __shared__ float2 tA[4096], tB[4096];
    __shared__ GateU mats[NQ];
    __shared__ float meas[NQ];
    __shared__ float lg[ADIM];
    __shared__ int lastflag;
    const int tid = threadIdx.x, blk = blockIdx.x;
    float4* psi4 = (float4*)psi;
    const int t0 = 2 * blk, t1 = 2 * blk + 1;

    float4 w0[4], w1[4];
    {
        const float4* ga0 = psi4 + (size_t)t0 * 2048;
        const float4* ga1 = psi4 + (size_t)t1 * 2048;
        for (int i = 0; i < 4; ++i) w0[i] = ga0[i * NT + tid];
        for (int i = 0; i < 4; ++i) w1[i] = ga1[i * NT + tid];
    }
    make_mats(mats, cp, layer, tid);
    __syncthreads();

    a_regscatter(tA, w0, mats, tid);
    __syncthreads();
    a_rounds(tA, mats, tid);

    if (layer < 3) {
        a_gatherstore(tA, psi4 + (size_t)t0 * 2048, t0, tid);   // overlaps t1 compute
        a_regscatter(tB, w1, mats, tid);
        __syncthreads();
        a_rounds(tB, mats, tid);
        a_gatherstore(tB, psi4 + (size_t)t1 * 2048, t1, tid);
    } else {
        float tot = 0.f, ones[NQ];
#pragma unroll
        for (int q = 0; q < NQ; ++q) ones[q] = 0.f;
        a_accum(tA, t0, tid, tot, ones);
        a_regscatter(tB, w1, mats, tid);
        __syncthreads();
        a_rounds(tB, mats, tid);
        a_accum(tB, t1, tid, tot, ones);

        for (int off = 32; off; off >>= 1) {
            tot += __shfl_down(tot, off, 64);
#pragma unroll
            for (int q = 0; q < NQ; ++q) ones[q] += __shfl_down(ones[q], off, 64);
        }
        __syncthreads();
        float* red = (float*)tA;
        int wv = tid >> 6, ln = tid & 63;
        if (ln == 0) {
            red[wv * 22 + 21] = tot;
#pragma unroll
            for (int q = 0; q < NQ; ++q) red[wv * 22 + q] = ones[q];
        }
        __syncthreads();
        if (tid < 22) {
            float s = 0.f;
            for (int wvi = 0; wvi < 8; ++wvi) s += red[wvi * 22 + tid];
            store4_sc(&partials[blk * 22 + tid], s);
        }
        drain_vmem();
        __syncthreads();
        if (tid == 0) lastflag = (atomicAdd(done, 1) == GB - 1);
        __syncthreads();
        if (!lastflag) return;

        // last block: reduce 256 partial rows (sc) -> meas -> head -> softmax
        float* red2 = (float*)tB;
        int col = tid % 22, grp = tid / 22;
        if (tid < 506) {
            float s = 0.f;
            for (int r = grp; r < GB; r += 23) s += load_sc_f(&partials[r * 22 + col]);
            red2[grp * 22 + col] = s;
        }
        __syncthreads();
        if (tid < 22) {
            float t2 = 0.f;
            for (int g = 0; g < 23; ++g) t2 += red2[g * 22 + tid];
            red2[600 + tid] = t2;
        }
        __syncthreads();
        if (tid < NQ) {
            float tt = red2[600 + 21];
            meas[tid] = (tt > 0.f) ? (1.f - 2.f * red2[600 + tid] / tt) : 1.f;
        }
        __syncthreads();
        if (tid < ADIM) {
            float s2 = head_b[tid];
            for (int q = 0; q < NQ; ++q) s2 += head_w[tid * NQ + q] * meas[q];
            lg[tid] = s2;
        }
        __syncthreads();
        if (tid == 0) {
            float m = lg[0];
            for (int a = 1; a < ADIM; ++a) m = fmaxf(m, lg[a]);
            float ssum = 0.f;
            for (int a = 0; a < ADIM; ++a) ssum += expf(lg[a] - m);
            float inv = 1.f / ssum;
            for (int a = 0; a < ADIM; ++a) out[a] = expf(lg[a] - m) * inv;
        }
    }
}

extern "C" void kernel_launch(void* const* d_in, const int* in_sizes, int n_in,
                              void* d_out, int out_size, void* d_ws, size_t ws_size,
                              hipStream_t stream) {
    const float* state   = (const float*)d_in[0];
    const float* cparams = (const float*)d_in[1];
    const float* head_w  = (const float*)d_in[2];
    const float* head_b  = (const float*)d_in[3];
    float* out = (float*)d_out;

    char* ws = (char*)d_ws;
    float2* psi      = (float2*)ws;
    float*  partials = (float*)(ws + (size_t)DIM * 8);
    int*    done     = (int*)(ws + (size_t)DIM * 8 + 32768);

    hipMemsetAsync(done, 0, 4, stream);
    for (int layer = 0; layer < NL; ++layer) {
        k_passB<<<GB, NT, 0, stream>>>(state, psi, cparams, layer);
        k_passA<<<GB, NT, 0, stream>>>(psi, cparams, layer, partials,
                                       head_w, head_b, out, done);
    }
}

// Round 12
// 196.554 us; speedup vs baseline: 1.2434x; 1.0051x over previous
//
#include <hip/hip_runtime.h>

// 21-qubit statevector policy net — per-phase kernels, software-pipelined.
// R12 = R11 + barrier-ordering fix: make_mats+sync BEFORE issuing global loads,
// so the scatter/round syncs no longer force vmcnt(0) drain of the second tile's
// hoisted loads (a __syncthreads implies s_waitcnt vmcnt(0) — R11 serialized there).
// done-memset folded into B0. All index algebra verbatim R7/R10/R11 (verified).
// ws: psi (2^21 float2, 16MB) | partials (256*22 f32) @16MB | done @16MB+32K
#define NQ 21
#define DIM (1 << NQ)
#define NL 4
#define ADIM 18
#define GB 256   // blocks per pass
#define NT 512

__device__ __forceinline__ float2 cfma2(float2 u0, float2 a, float2 u1, float2 b) {
    return make_float2(u0.x * a.x - u0.y * a.y + u1.x * b.x - u1.y * b.y,
                       u0.x * a.y + u0.y * a.x + u1.x * b.y + u1.y * b.x);
}

struct GateU { float2 u00, u01, u10, u11; };

__device__ __forceinline__ void bfly(float2& a, float2& b, const GateU& U) {
    float2 na = cfma2(U.u00, a, U.u01, b);
    float2 nb = cfma2(U.u10, a, U.u11, b);
    a = na; b = nb;
}

// LDS bank swizzle (verified R6/R7/R10)
__device__ __forceinline__ int sw(int j) { return j ^ (((j >> 4) & 7) << 1); }

// sc0 sc1 = LLC-coherent, XCD-L2 bypass (verified R9)
__device__ __forceinline__ void store4_sc(float* p, float v) {
    asm volatile("global_store_dword %0, %1, off sc0 sc1" :: "v"(p), "v"(v) : "memory");
}
__device__ __forceinline__ float load_sc_f(const float* p) {
    float r;
    asm volatile("global_load_dword %0, %1, off sc0 sc1\n\ts_waitcnt vmcnt(0)"
                 : "=v"(r) : "v"(p) : "memory");
    return r;
}
__device__ __forceinline__ void drain_vmem() {
    asm volatile("s_waitcnt vmcnt(0)" ::: "memory");
}

// threads 0..20: fused U = RZ*RY*RX for this layer
__device__ __forceinline__ void make_mats(GateU* mats, const float* __restrict__ cp, int layer, int tid) {
    if (tid < NQ) {
        const float* ang = cp + (layer * NQ + tid) * 3;
        float a = ang[0], b = ang[1], c = ang[2];
        float ca = cosf(0.5f * a), sa = sinf(0.5f * a);
        float cb = cosf(0.5f * b), sb = sinf(0.5f * b);
        float cc = cosf(0.5f * c), sc = sinf(0.5f * c);
        float2 m00 = make_float2(cb * ca,  sb * sa);
        float2 m01 = make_float2(-sb * ca, -cb * sa);
        float2 m10 = make_float2(sb * ca,  -cb * sa);
        float2 m11 = make_float2(cb * ca,  -sb * sa);
        GateU U;
        U.u00 = make_float2(cc * m00.x + sc * m00.y, cc * m00.y - sc * m00.x);
        U.u01 = make_float2(cc * m01.x + sc * m01.y, cc * m01.y - sc * m01.x);
        U.u10 = make_float2(cc * m10.x - sc * m10.y, cc * m10.y + sc * m10.x);
        U.u11 = make_float2(cc * m11.x - sc * m11.y, cc * m11.y + sc * m11.x);
        mats[tid] = U;
    }
}

// radix-8 round: 3 gates per LDS round-trip (verified R7)
__device__ __forceinline__ void round3(float2* tile, int tid, int g,
                                       GateU Ua, GateU Ub, GateU Uc) {
    int bl = (1 << g) - 1;
    int base = (tid & bl) | ((tid >> g) << (g + 3));
    float2 v[8];
#pragma unroll
    for (int j = 0; j < 8; ++j) v[j] = tile[sw(base + (j << g))];
#pragma unroll
    for (int s = 0; s < 8; s += 2) bfly(v[s], v[s + 1], Ua);
#pragma unroll
    for (int s = 0; s < 8; ++s) if (!(s & 2)) bfly(v[s], v[s | 2], Ub);
#pragma unroll
    for (int s = 0; s < 8; ++s) if (!(s & 4)) bfly(v[s], v[s | 4], Uc);
#pragma unroll
    for (int j = 0; j < 8; ++j) tile[sw(base + (j << g))] = v[j];
    __syncthreads();
}

// ===== B pass (verified R10/R11 algebra): complex idx = (h<<12)|(blk<<4)|l; h = bits 12..20
// (9 bits, qubits 0..8), blk = bits 4..11, l = bits 0..3. Two l-halves, dual LDS buffers.
__global__ __launch_bounds__(NT, 2) void k_passB(const float* __restrict__ state,
                                                 float2* __restrict__ psi,
                                                 const float* __restrict__ cp, int layer,
                                                 int* __restrict__ done) {
    __shared__ float2 tA[4096], tB[4096];
    __shared__ GateU mats[NQ];
    const int tid = threadIdx.x, blk = blockIdx.x;
    float4* psi4 = (float4*)psi;
    const int srcmask = (layer < 3) ? 0xFF : 0;

    // mats FIRST, then its barrier, so later syncs don't drain hoisted loads at vmcnt(0)
    make_mats(mats, cp, layer, tid);
    if (layer == 0 && blk == 0 && tid == 32) *done = 0;   // for A3's last-block fold
    __syncthreads();

    float4 wA[4], wB[4];
    if (layer == 0) {
        const float4* s4 = (const float4*)state;
        for (int i = 0; i < 2; ++i) {
            int f = i * NT + tid, d = f & 1, h = f >> 1;
            wA[i] = s4[(h << 10) | (blk << 2) | d];
            wB[i] = s4[(h << 10) | (blk << 2) | (2 + d)];
        }
    } else {
        for (int i = 0; i < 4; ++i) {
            int f = i * NT + tid, c = f & 3, h = f >> 2;
            wA[i] = psi4[(h << 11) | (blk << 3) | c];
            wB[i] = psi4[(h << 11) | (blk << 3) | (4 + c)];
        }
    }

    // scatter half 0 -> tA (uses wA only; wB still in flight)
    if (layer == 0) {
        float4* t4 = (float4*)tA;
        for (int i = 0; i < 2; ++i) {
            int f = i * NT + tid, d = f & 1, h = f >> 1;
            int j = (h << 3) | (4 * d);
            float4 w = wA[i];
            t4[sw(j) >> 1]     = make_float4(w.x, 0.f, w.y, 0.f);
            t4[sw(j + 2) >> 1] = make_float4(w.z, 0.f, w.w, 0.f);
        }
    } else {
        for (int i = 0; i < 4; ++i) {
            int f = i * NT + tid, c = f & 3, h = f >> 2;
            int se = (h << 3) | (2 * c);
            float4 w = wA[i];
            // c4 (prev layer's CNOT ctrl q20 -> tgt q0): l odd => flip bit 20 = slot bit 11
            tA[sw(se)]              = make_float2(w.x, w.y);
            tA[sw((se + 1) ^ 2048)] = make_float2(w.z, w.w);
        }
    }
    __syncthreads();
    round3(tA, tid, 3, mats[8], mats[7], mats[6]);
    round3(tA, tid, 6, mats[5], mats[4], mats[3]);
    round3(tA, tid, 9, mats[2], mats[1], mats[0]);

    // store half 0 (chain gather: src h = h ^ ((h>>1)&mask)) + scatter half 1 -> tB
    for (int i = 0; i < 4; ++i) {
        int f = i * NT + tid, c = f & 3, h = f >> 2;
        int hs = h ^ ((h >> 1) & srcmask);
        int s = (hs << 3) | (2 * c);
        float2 e0 = tA[sw(s)], e1 = tA[sw(s + 1)];
        psi4[(h << 11) | (blk << 3) | c] = make_float4(e0.x, e0.y, e1.x, e1.y);
    }
    if (layer == 0) {
        float4* t4 = (float4*)tB;
        for (int i = 0; i < 2; ++i) {
            int f = i * NT + tid, d = f & 1, h = f >> 1;
            int j = (h << 3) | (4 * d);
            float4 w = wB[i];
            t4[sw(j) >> 1]     = make_float4(w.x, 0.f, w.y, 0.f);
            t4[sw(j + 2) >> 1] = make_float4(w.z, 0.f, w.w, 0.f);
        }
    } else {
        for (int i = 0; i < 4; ++i) {
            int f = i * NT + tid, c = f & 3, h = f >> 2;
            int se = (h << 3) | (2 * c);
            float4 w = wB[i];
            tB[sw(se)]              = make_float2(w.x, w.y);
            tB[sw((se + 1) ^ 2048)] = make_float2(w.z, w.w);
        }
    }
    __syncthreads();
    round3(tB, tid, 3, mats[8], mats[7], mats[6]);
    round3(tB, tid, 6, mats[5], mats[4], mats[3]);
    round3(tB, tid, 9, mats[2], mats[1], mats[0]);
    for (int i = 0; i < 4; ++i) {
        int f = i * NT + tid, c = f & 3, h = f >> 2;
        int hs = h ^ ((h >> 1) & srcmask);
        int s = (hs << 3) | (2 * c);
        float2 e0 = tB[sw(s)], e1 = tB[sw(s + 1)];
        psi4[(h << 11) | (blk << 3) | (4 + c)] = make_float4(e0.x, e0.y, e1.x, e1.y);
    }
}

// regscatter for A pass (verbatim R7/R11): reg gates q20,q10,q9 then LDS scatter
__device__ __forceinline__ void a_regscatter(float2* tile, const float4* w,
                                             const GateU* mats, int tid) {
    float2 v[8];
    float4* t4 = (float4*)tile;
#pragma unroll
    for (int i = 0; i < 4; ++i) {
        v[2 * i]     = make_float2(w[i].x, w[i].y);
        v[2 * i + 1] = make_float2(w[i].z, w[i].w);
    }
    GateU U20 = mats[20];
#pragma unroll
    for (int s = 0; s < 8; s += 2) bfly(v[s], v[s + 1], U20);
    GateU U10 = mats[10];
#pragma unroll
    for (int s = 0; s < 8; ++s) if (!(s & 2)) bfly(v[s], v[s | 2], U10);
    GateU U9 = mats[9];
#pragma unroll
    for (int s = 0; s < 8; ++s) if (!(s & 4)) bfly(v[s], v[s | 4], U9);
    for (int i = 0; i < 4; ++i)
        t4[sw(2 * (i * NT + tid)) >> 1] =
            make_float4(v[2 * i].x, v[2 * i].y, v[2 * i + 1].x, v[2 * i + 1].y);
}

__device__ __forceinline__ void a_rounds(float2* tile, const GateU* mats, int tid) {
    round3(tile, tid, 1, mats[19], mats[18], mats[17]);
    round3(tile, tid, 4, mats[16], mats[15], mats[14]);
    round3(tile, tid, 7, mats[13], mats[12], mats[11]);
}

// gather-store with boundary CNOT + A-local chain (verbatim R7)
__device__ __forceinline__ void a_gatherstore(float2* tile, float4* oa, int t, int tid) {
    int cb = (t & 1) << 11;
    for (int i = 0; i < 4; ++i) {
        int f = i * NT + tid;
        int s0 = ((2 * f) ^ (f & 0x7FF)) ^ cb;
        float2 e0 = tile[sw(s0)], e1 = tile[sw(s0 ^ 1)];
        oa[f] = make_float4(e0.x, e0.y, e1.x, e1.y);
    }
}

__device__ __forceinline__ void a_accum(float2* tile, int t, int tid,
                                        float& tot, float* ones) {
    for (int it = 0; it < 8; ++it) {
        int j = it * NT + tid;
        float2 a2 = tile[sw(j)];
        float pr = a2.x * a2.x + a2.y * a2.y;
        int gidx = (t << 12) | j;
        tot += pr;
#pragma unroll
        for (int q = 0; q < NQ; ++q)
            ones[q] += pr * (float)((gidx >> (20 - q)) & 1);
    }
}

// A pass: bits 0..11 local (qubits 9..20); tiles t0=2blk, t1=2blk+1 pipelined.
// Layer 3: measurement + last-block-done final (head+softmax) folded in.
__global__ __launch_bounds__(NT, 2) void k_passA(float2* __restrict__ psi,
                                                 const float* __restrict__ cp, int layer,
                                                 float* __restrict__ partials,
                                                 const float* __restrict__ head_w,
                                                 const float* __restrict__ head_b,
                                                 float* __restrict__ out,
                                                 int* __restrict__ done) {
    __shared__ float2 tA[4096], tB[4096];
    __shared__ GateU mats[NQ];
    __shared__ float meas[NQ];
    __shared__ float lg[ADIM];
    __shared__ int lastflag;
    const int tid = threadIdx.x, blk = blockIdx.x;
    float4* psi4 = (float4*)psi;
    const int t0 = 2 * blk, t1 = 2 * blk + 1;

    // mats FIRST + barrier; loads issued after, so tile-1 loads stay in flight
    // under tile-0 compute (syncs below only drain what's already consumed).
    make_mats(mats, cp, layer, tid);
    __syncthreads();

    float4 w0[4], w1[4];
    {
        const float4* ga0 = psi4 + (size_t)t0 * 2048;
        const float4* ga1 = psi4 + (size_t)t1 * 2048;
        for (int i = 0; i < 4; ++i) w0[i] = ga0[i * NT + tid];
        for (int i = 0; i < 4; ++i) w1[i] = ga1[i * NT + tid];
    }

    a_regscatter(tA, w0, mats, tid);
    __syncthreads();
    a_rounds(tA, mats, tid);

    if (layer < 3) {
        a_gatherstore(tA, psi4 + (size_t)t0 * 2048, t0, tid);   // overlaps t1 compute
        a_regscatter(tB, w1, mats, tid);
        __syncthreads();
        a_rounds(tB, mats, tid);
        a_gatherstore(tB, psi4 + (size_t)t1 * 2048, t1, tid);
    } else {
        float tot = 0.f, ones[NQ];
#pragma unroll
        for (int q = 0; q < NQ; ++q) ones[q] = 0.f;
        a_accum(tA, t0, tid, tot, ones);
        a_regscatter(tB, w1, mats, tid);
        __syncthreads();
        a_rounds(tB, mats, tid);
        a_accum(tB, t1, tid, tot, ones);

        for (int off = 32; off; off >>= 1) {
            tot += __shfl_down(tot, off, 64);
#pragma unroll
            for (int q = 0; q < NQ; ++q) ones[q] += __shfl_down(ones[q], off, 64);
        }
        __syncthreads();
        float* red = (float*)tA;
        int wv = tid >> 6, ln = tid & 63;
        if (ln == 0) {
            red[wv * 22 + 21] = tot;
#pragma unroll
            for (int q = 0; q < NQ; ++q) red[wv * 22 + q] = ones[q];
        }
        __syncthreads();
        if (tid < 22) {
            float s = 0.f;
            for (int wvi = 0; wvi < 8; ++wvi) s += red[wvi * 22 + tid];
            store4_sc(&partials[blk * 22 + tid], s);
        }
        drain_vmem();
        __syncthreads();
        if (tid == 0) lastflag = (atomicAdd(done, 1) == GB - 1);
        __syncthreads();
        if (!lastflag) return;

        // last block: reduce 256 partial rows (sc) -> meas -> head -> softmax
        float* red2 = (float*)tB;
        int col = tid % 22, grp = tid / 22;
        if (tid < 506) {
            float s = 0.f;
            for (int r = grp; r < GB; r += 23) s += load_sc_f(&partials[r * 22 + col]);
            red2[grp * 22 + col] = s;
        }
        __syncthreads();
        if (tid < 22) {
            float t2 = 0.f;
            for (int g = 0; g < 23; ++g) t2 += red2[g * 22 + tid];
            red2[600 + tid] = t2;
        }
        __syncthreads();
        if (tid < NQ) {
            float tt = red2[600 + 21];
            meas[tid] = (tt > 0.f) ? (1.f - 2.f * red2[600 + tid] / tt) : 1.f;
        }
        __syncthreads();
        if (tid < ADIM) {
            float s2 = head_b[tid];
            for (int q = 0; q < NQ; ++q) s2 += head_w[tid * NQ + q] * meas[q];
            lg[tid] = s2;
        }
        __syncthreads();
        if (tid == 0) {
            float m = lg[0];
            for (int a = 1; a < ADIM; ++a) m = fmaxf(m, lg[a]);
            float ssum = 0.f;
            for (int a = 0; a < ADIM; ++a) ssum += expf(lg[a] - m);
            float inv = 1.f / ssum;
            for (int a = 0; a < ADIM; ++a) out[a] = expf(lg[a] - m) * inv;
        }
    }
}

extern "C" void kernel_launch(void* const* d_in, const int* in_sizes, int n_in,
                              void* d_out, int out_size, void* d_ws, size_t ws_size,
                              hipStream_t stream) {
    const float* state   = (const float*)d_in[0];
    const float* cparams = (const float*)d_in[1];
    const float* head_w  = (const float*)d_in[2];
    const float* head_b  = (const float*)d_in[3];
    float* out = (float*)d_out;

    char* ws = (char*)d_ws;
    float2* psi      = (float2*)ws;
    float*  partials = (float*)(ws + (size_t)DIM * 8);
    int*    done     = (int*)(ws + (size_t)DIM * 8 + 32768);

    for (int layer = 0; layer < NL; ++layer) {
        k_passB<<<GB, NT, 0, stream>>>(state, psi, cparams, layer, done);
        k_passA<<<GB, NT, 0, stream>>>(psi, cparams, layer, partials,
                                       head_w, head_b, out, done);
    }
}